// Round 10
// baseline (11050.386 us; speedup 1.0000x reference)
//
#include <hip/hip_runtime.h>

#define LSTM_B   4096
#define LSTM_H   1024
#define LSTM_IN  512
#define LSTM_OUT 512

typedef unsigned long long u64;
typedef unsigned int u32;

__device__ __forceinline__ u64 aload(u64* p) {
  return __hip_atomic_load(p, __ATOMIC_RELAXED, __HIP_MEMORY_SCOPE_AGENT);
}
__device__ __forceinline__ void astore(u64* p, u64 v) {
  __hip_atomic_store(p, v, __ATOMIC_RELAXED, __HIP_MEMORY_SCOPE_AGENT);
}
__device__ __forceinline__ u64 packft(float f, u32 tag) {
  return ((u64)tag << 32) | (u64)__float_as_uint(f);
}
__device__ __forceinline__ float dot4f(float4 a, float4 b) {
  return fmaf(a.x, b.x, fmaf(a.y, b.y, fmaf(a.z, b.z, a.w * b.w)));
}
// fast activations: v_exp_f32 + v_rcp_f32. |rel err| ~1e-6, bounded outputs.
__device__ __forceinline__ float fsig(float x) {
  return __builtin_amdgcn_rcpf(1.0f + __expf(-x));
}
__device__ __forceinline__ float ftanh(float x) {
  return 1.0f - 2.0f * __builtin_amdgcn_rcpf(1.0f + __expf(2.0f * x));
}
// Force the just-issued critical store out of the WC buffer before moving on.
// R5 lesson: without this the store lingers -> every consumer's detect slips,
// poll traffic triples, dur 9.6->28ms.
// R8 lesson: do NOT issue speculative loads after it either — any carried
// in-flight load serializes the next poll start via vmcnt ordering.
__device__ __forceinline__ void drain_vmem() {
  asm volatile("s_waitcnt vmcnt(0)" ::: "memory");
}

// Pin a loaded value into registers (opaque to the optimizer; can't be
// rematerialized as a memory load inside the loop).
__device__ __forceinline__ float4 pin4(float4 v) {
  float4 r;
  asm volatile("v_mov_b32 %0, %4\n\t"
               "v_mov_b32 %1, %5\n\t"
               "v_mov_b32 %2, %6\n\t"
               "v_mov_b32 %3, %7"
               : "=v"(r.x), "=v"(r.y), "=v"(r.z), "=v"(r.w)
               : "v"(v.x), "v"(v.y), "v"(v.z), "v"(v.w));
  return r;
}
__device__ __forceinline__ float pin1(float v) {
  float r;
  asm volatile("v_mov_b32 %0, %1" : "=v"(r) : "v"(v));
  return r;
}

// wave64 sum on the VALU pipe via DPP. Result valid in lane 63 ONLY.
template <int CTRL, int RM>
__device__ __forceinline__ float dpp_add(float x) {
  return x + __int_as_float(
      __builtin_amdgcn_update_dpp(0, __float_as_int(x), CTRL, RM, 0xf, true));
}
__device__ __forceinline__ float wsum63(float x) {
  x = dpp_add<0x111, 0xf>(x);   // row_shr:1
  x = dpp_add<0x112, 0xf>(x);   // row_shr:2
  x = dpp_add<0x114, 0xf>(x);   // row_shr:4
  x = dpp_add<0x118, 0xf>(x);   // row_shr:8  -> lanes 15/31/47/63 = row sums
  x = dpp_add<0x142, 0xa>(x);   // row_bcast:15 -> lane31, lane63 partials
  x = dpp_add<0x143, 0xc>(x);   // row_bcast:31 -> lane63 = total
  return x;
}

// ---------------- transpose fc_w [512,1024] -> fcwT [1024,512] ----------------
__global__ void k_transpose(const float* __restrict__ w, float* __restrict__ wT) {
  int idx = blockIdx.x * 256 + threadIdx.x;   // 512*1024 total
  int k = idx >> 9;
  int o = idx & 511;
  wT[idx] = w[o * 1024 + k];
}

// ---------------- persistent recurrent kernel ----------------
// 256 blocks x 512 threads (8 waves, 1 block/CU, 2 waves/SIMD).
// Blocks 0..127: layer-0, block bx owns units 8bx..8bx+7 (one per wave).
// Blocks 128..255: layer-1, same mapping.
// R4 structure (9.54 ms verified): tagged u64 slots, contiguous 32B chunk per
// polling thread, serial incremental poll with s_sleep(1), vmcnt(0) drain
// after critical stores, DPP reduce. L1 splits polling: threads 0-255 own h0
// chunks, 256-511 own h1 chunks.
// NEW vs R4: line-aggregated store. The block's 8 unit-values funnel through
// LDS; threads 0-7 (one wave, contiguous lanes) issue the 64B line as ONE
// coalesced transaction. Previously 8 independent 8B stores from 8 waves
// dribbled into the line -> consumers' 4-tag chunk checks passed partially,
// costing extra ~RTT poll rounds per step on the rate-setting h1 chain.
// R5-R8 all regressed trying to shave CONSUMER-side detect latency; do not
// add speculative loads to the poll loop.
__global__ __launch_bounds__(512)
__attribute__((amdgpu_waves_per_eu(2, 2)))
void k_recur(
    const float* __restrict__ x,
    const float* __restrict__ Whh0, const float* __restrict__ Wih0,
    const float* __restrict__ bih0, const float* __restrict__ bhh0,
    const float* __restrict__ Wih1, const float* __restrict__ Whh1,
    const float* __restrict__ bih1, const float* __restrict__ bhh1,
    const float* __restrict__ h0in, const float* __restrict__ c0in,
    u64* __restrict__ h0buf, u64* __restrict__ h1buf)
{
  __shared__ float h0s[2][LSTM_H];
  __shared__ float h1s[2][LSTM_H];   // layer-1 blocks only
  __shared__ u64 hout[8];            // per-step line-aggregation staging

  const int tid = threadIdx.x;       // 0..511
  const int w = tid >> 6, l = tid & 63;
  const bool lay1 = (blockIdx.x >= 128);
  const int bx = lay1 ? (int)blockIdx.x - 128 : (int)blockIdx.x;
  const int hd = 8 * bx + w;         // this wave's output unit

  if (!lay1) {
    // ===================== layer-0 blocks =====================
    float4 Whr[4][4];                // Whh0 rows for unit hd
    float  Wxr[4][8];                // Wih0; lane l holds cols l+64m
#pragma unroll
    for (int g = 0; g < 4; ++g) {
#pragma unroll
      for (int q = 0; q < 4; ++q)
        Whr[g][q] = pin4(*(const float4*)&Whh0[(size_t)(g * 1024 + hd) * 1024 + q * 256 + 4 * l]);
#pragma unroll
      for (int m = 0; m < 8; ++m)
        Wxr[g][m] = pin1(Wih0[(size_t)(g * 1024 + hd) * 512 + 64 * m + l]);
    }
    float bsum[4];
#pragma unroll
    for (int g = 0; g < 4; ++g) bsum[g] = bih0[g * 1024 + hd] + bhh0[g * 1024 + hd];
    float c = c0in[hd];

    h0s[1][tid]       = h0in[tid];
    h0s[1][tid + 512] = h0in[tid + 512];
    __syncthreads();

    // step 0: f(h0_init, x[0]) -> h0buf slot 0, tag 0 (line-aggregated)
    {
      float a0 = 0.f, a1 = 0.f, a2 = 0.f, a3 = 0.f;
#pragma unroll
      for (int m = 0; m < 8; ++m) {
        float xv = x[64 * m + l];
        a0 = fmaf(Wxr[0][m], xv, a0);
        a1 = fmaf(Wxr[1][m], xv, a1);
        a2 = fmaf(Wxr[2][m], xv, a2);
        a3 = fmaf(Wxr[3][m], xv, a3);
      }
#pragma unroll
      for (int q = 0; q < 4; ++q) {
        float4 hq = *(const float4*)&h0s[1][q * 256 + 4 * l];
        a0 += dot4f(Whr[0][q], hq);
        a1 += dot4f(Whr[1][q], hq);
        a2 += dot4f(Whr[2][q], hq);
        a3 += dot4f(Whr[3][q], hq);
      }
      a0 = wsum63(a0); a1 = wsum63(a1); a2 = wsum63(a2); a3 = wsum63(a3);
      c = fsig(a1 + bsum[1]) * c + fsig(a0 + bsum[0]) * ftanh(a2 + bsum[2]);
      float hn = fsig(a3 + bsum[3]) * ftanh(c);
      if (l == 63) hout[w] = packft(hn, 0u);   // lane 63 holds real sums
      __syncthreads();
      if (tid < 8) astore(&h0buf[8 * bx + tid], hout[tid]);
      drain_vmem();
    }

    u64* p = &h0buf[4 * tid];        // valid for tid<256 (chunk units 4tid..+3)
#pragma unroll 1
    for (int t = 0; t < LSTM_B - 1; ++t, p += 1024) {
      const int buf = t & 1;
      const u32 tt = (u32)t;
      // x(t+1) partial gates: off the critical chain, overlaps peers' flight.
      float a0 = 0.f, a1 = 0.f, a2 = 0.f, a3 = 0.f;
#pragma unroll
      for (int m = 0; m < 8; ++m) {
        float xv = x[(size_t)(t + 1) * 512 + 64 * m + l];
        a0 = fmaf(Wxr[0][m], xv, a0);
        a1 = fmaf(Wxr[1][m], xv, a1);
        a2 = fmaf(Wxr[2][m], xv, a2);
        a3 = fmaf(Wxr[3][m], xv, a3);
      }
      // waves 0-3 poll h0(t) chunks; waves 4-7 go straight to the barrier
      if (tid < 256) {
        u64 va = 0, vb = 0, vc = 0, vd = 0;
        bool da = false, db = false, dc = false, dd = false;
        for (;;) {
          if (!da) { va = aload(p);     da = ((u32)(va >> 32) == tt); }
          if (!db) { vb = aload(p + 1); db = ((u32)(vb >> 32) == tt); }
          if (!dc) { vc = aload(p + 2); dc = ((u32)(vc >> 32) == tt); }
          if (!dd) { vd = aload(p + 3); dd = ((u32)(vd >> 32) == tt); }
          if (__all(da && db && dc && dd)) break;
          __builtin_amdgcn_s_sleep(1);
        }
        float4 hv;
        hv.x = __uint_as_float((u32)va);
        hv.y = __uint_as_float((u32)vb);
        hv.z = __uint_as_float((u32)vc);
        hv.w = __uint_as_float((u32)vd);
        *(float4*)&h0s[buf][4 * tid] = hv;
      }
      __syncthreads();
#pragma unroll
      for (int q = 0; q < 4; ++q) {
        float4 hq = *(const float4*)&h0s[buf][q * 256 + 4 * l];
        a0 += dot4f(Whr[0][q], hq);
        a1 += dot4f(Whr[1][q], hq);
        a2 += dot4f(Whr[2][q], hq);
        a3 += dot4f(Whr[3][q], hq);
      }
      a0 = wsum63(a0); a1 = wsum63(a1); a2 = wsum63(a2); a3 = wsum63(a3);
      c = fsig(a1 + bsum[1]) * c + fsig(a0 + bsum[0]) * ftanh(a2 + bsum[2]);
      float hn = fsig(a3 + bsum[3]) * ftanh(c);
      // line-aggregated store: funnel 8 wave results through LDS, one wave
      // issues the whole 64B line as a single coalesced transaction.
      if (l == 63) hout[w] = packft(hn, tt + 1);
      __syncthreads();
      if (tid < 8) astore(&h0buf[(size_t)(t + 1) * 1024 + 8 * bx + tid], hout[tid]);
      drain_vmem();
    }
  } else {
    // ===================== layer-1 blocks =====================
    float4 Wi[4][4], Wh[4][4];
#pragma unroll
    for (int g = 0; g < 4; ++g)
#pragma unroll
      for (int q = 0; q < 4; ++q) {
        Wi[g][q] = pin4(*(const float4*)&Wih1[(size_t)(g * 1024 + hd) * 1024 + q * 256 + 4 * l]);
        Wh[g][q] = pin4(*(const float4*)&Whh1[(size_t)(g * 1024 + hd) * 1024 + q * 256 + 4 * l]);
      }
    float bsum[4];
#pragma unroll
    for (int g = 0; g < 4; ++g) bsum[g] = bih1[g * 1024 + hd] + bhh1[g * 1024 + hd];
    float c = c0in[1024 + hd];
    // seed h1(init), tag 0 — line-aggregated like the loop stores
    if (l == 0) hout[w] = packft(h0in[1024 + hd], 0u);
    __syncthreads();
    if (tid < 8) astore(&h1buf[8 * bx + tid], hout[tid]);
    drain_vmem();

    // split polling: threads 0-255 own h0 chunk 4*tid; 256-511 own h1 chunk
    const bool ish0 = (tid < 256);
    const int ci = ish0 ? 4 * tid : 4 * (tid - 256);
    u64* p = ish0 ? &h0buf[ci] : &h1buf[ci];
#pragma unroll 1
    for (int t = 0; t < LSTM_B; ++t, p += 1024) {
      const int buf = t & 1;
      const u32 tt = (u32)t;
      // concurrent polls (h0 passes ~instantly since L0 runs ahead; h1 is the
      // rate-setter). ONE serial wait + ONE barrier before the dot.
      {
        u64 va = 0, vb = 0, vc = 0, vd = 0;
        bool da = false, db = false, dc = false, dd = false;
        for (;;) {
          if (!da) { va = aload(p);     da = ((u32)(va >> 32) == tt); }
          if (!db) { vb = aload(p + 1); db = ((u32)(vb >> 32) == tt); }
          if (!dc) { vc = aload(p + 2); dc = ((u32)(vc >> 32) == tt); }
          if (!dd) { vd = aload(p + 3); dd = ((u32)(vd >> 32) == tt); }
          if (__all(da && db && dc && dd)) break;
          __builtin_amdgcn_s_sleep(1);
        }
        float4 hv;
        hv.x = __uint_as_float((u32)va);
        hv.y = __uint_as_float((u32)vb);
        hv.z = __uint_as_float((u32)vc);
        hv.w = __uint_as_float((u32)vd);
        if (ish0) *(float4*)&h0s[buf][ci] = hv;
        else      *(float4*)&h1s[buf][ci] = hv;
      }
      __syncthreads();
      float a0 = 0.f, a1 = 0.f, a2 = 0.f, a3 = 0.f;
#pragma unroll
      for (int q = 0; q < 4; ++q) {
        float4 hq = *(const float4*)&h0s[buf][q * 256 + 4 * l];
        a0 += dot4f(Wi[0][q], hq);
        a1 += dot4f(Wi[1][q], hq);
        a2 += dot4f(Wi[2][q], hq);
        a3 += dot4f(Wi[3][q], hq);
      }
#pragma unroll
      for (int q = 0; q < 4; ++q) {
        float4 hq = *(const float4*)&h1s[buf][q * 256 + 4 * l];
        a0 += dot4f(Wh[0][q], hq);
        a1 += dot4f(Wh[1][q], hq);
        a2 += dot4f(Wh[2][q], hq);
        a3 += dot4f(Wh[3][q], hq);
      }
      a0 = wsum63(a0); a1 = wsum63(a1); a2 = wsum63(a2); a3 = wsum63(a3);
      c = fsig(a1 + bsum[1]) * c + fsig(a0 + bsum[0]) * ftanh(a2 + bsum[2]);
      float hn = fsig(a3 + bsum[3]) * ftanh(c);
      // line-aggregated store of h1(t+1)
      if (l == 63) hout[w] = packft(hn, tt + 1);
      __syncthreads();
      if (tid < 8) astore(&h1buf[(size_t)(t + 1) * 1024 + 8 * bx + tid], hout[tid]);
      drain_vmem();
    }
  }
}

// ---------------- FC + softmax: 16 timesteps per block ----------------
__global__ __launch_bounds__(256) void k_fc(u64* __restrict__ h1buf,
                                            const float* __restrict__ fcwT,
                                            const float* __restrict__ fcb,
                                            float* __restrict__ out) {
  __shared__ float smem[16 * 1024];
  const int tid = threadIdx.x;
  const int t0 = blockIdx.x * 16;

  for (int i = 0; i < 64; ++i) {
    int e = tid + 256 * i;
    int tt = e >> 10, k = e & 1023;
    u64 v = aload(&h1buf[(size_t)(t0 + tt + 1) * 1024 + k]);
    smem[e] = __uint_as_float((u32)v);
  }
  __syncthreads();

  float acc0[16], acc1[16];
#pragma unroll
  for (int tt = 0; tt < 16; ++tt) { acc0[tt] = 0.f; acc1[tt] = 0.f; }

  for (int k0 = 0; k0 < 1024; k0 += 4) {
    float4 w0v, w1v;
    w0v.x = fcwT[(k0 + 0) * 512 + tid];       w1v.x = fcwT[(k0 + 0) * 512 + 256 + tid];
    w0v.y = fcwT[(k0 + 1) * 512 + tid];       w1v.y = fcwT[(k0 + 1) * 512 + 256 + tid];
    w0v.z = fcwT[(k0 + 2) * 512 + tid];       w1v.z = fcwT[(k0 + 2) * 512 + 256 + tid];
    w0v.w = fcwT[(k0 + 3) * 512 + tid];       w1v.w = fcwT[(k0 + 3) * 512 + 256 + tid];
    float4 hv[16];
#pragma unroll
    for (int tt = 0; tt < 16; ++tt) hv[tt] = *(const float4*)&smem[tt * 1024 + k0];
#pragma unroll
    for (int tt = 0; tt < 16; ++tt) {
      acc0[tt] += dot4f(w0v, hv[tt]);
      acc1[tt] += dot4f(w1v, hv[tt]);
    }
  }
  float bb0 = fcb[tid], bb1 = fcb[tid + 256];
  __syncthreads();  // done reading h1 tile; alias smem as logits [16][512]
#pragma unroll
  for (int tt = 0; tt < 16; ++tt) {
    smem[tt * 512 + tid] = acc0[tt] + bb0;
    smem[tt * 512 + 256 + tid] = acc1[tt] + bb1;
  }
  __syncthreads();

  const int wv = tid >> 6, l = tid & 63;
  for (int r = 0; r < 4; ++r) {
    int tt = wv * 4 + r;
    float v[8];
    float mx = -3.4e38f;
#pragma unroll
    for (int m = 0; m < 8; ++m) { v[m] = smem[tt * 512 + m * 64 + l]; mx = fmaxf(mx, v[m]); }
#pragma unroll
    for (int s = 1; s < 64; s <<= 1) mx = fmaxf(mx, __shfl_xor(mx, s, 64));
    float sum = 0.f;
#pragma unroll
    for (int m = 0; m < 8; ++m) { v[m] = expf(v[m] - mx); sum += v[m]; }
#pragma unroll
    for (int s = 1; s < 64; s <<= 1) sum += __shfl_xor(sum, s, 64);
    float inv = 1.0f / sum;
#pragma unroll
    for (int m = 0; m < 8; ++m) out[(size_t)(t0 + tt) * 512 + m * 64 + l] = v[m] * inv;
  }
}

extern "C" void kernel_launch(void* const* d_in, const int* in_sizes, int n_in,
                              void* d_out, int out_size, void* d_ws, size_t ws_size,
                              hipStream_t stream) {
  const float* x    = (const float*)d_in[0];
  const float* Wih0 = (const float*)d_in[1];
  const float* Whh0 = (const float*)d_in[2];
  const float* bih0 = (const float*)d_in[3];
  const float* bhh0 = (const float*)d_in[4];
  const float* Wih1 = (const float*)d_in[5];
  const float* Whh1 = (const float*)d_in[6];
  const float* bih1 = (const float*)d_in[7];
  const float* bhh1 = (const float*)d_in[8];
  const float* h0in = (const float*)d_in[9];
  const float* c0in = (const float*)d_in[10];
  const float* fcw  = (const float*)d_in[11];
  const float* fcb  = (const float*)d_in[12];
  float* out = (float*)d_out;

  // workspace: h0buf (B slots) | h1buf (B+1 slots) | fcwT  -> ~69 MB
  u64* h0buf = (u64*)d_ws;
  u64* h1buf = h0buf + (size_t)LSTM_B * 1024;
  float* fcwT = (float*)(h1buf + (size_t)(LSTM_B + 1) * 1024);

  hipLaunchKernelGGL(k_transpose, dim3((512 * 1024) / 256), dim3(256), 0, stream, fcw, fcwT);
  hipLaunchKernelGGL(k_recur, dim3(256), dim3(512), 0, stream,
                     x, Whh0, Wih0, bih0, bhh0, Wih1, Whh1, bih1, bhh1,
                     h0in, c0in, h0buf, h1buf);
  hipLaunchKernelGGL(k_fc, dim3(LSTM_B / 16), dim3(256), 0, stream, h1buf, fcwT, fcb, out);
}

// Round 11
// 9522.582 us; speedup vs baseline: 1.1604x; 1.1604x over previous
//
#include <hip/hip_runtime.h>

#define LSTM_B   4096
#define LSTM_H   1024
#define LSTM_IN  512
#define LSTM_OUT 512

typedef unsigned long long u64;
typedef unsigned int u32;

__device__ __forceinline__ u64 aload(u64* p) {
  return __hip_atomic_load(p, __ATOMIC_RELAXED, __HIP_MEMORY_SCOPE_AGENT);
}
__device__ __forceinline__ void astore(u64* p, u64 v) {
  __hip_atomic_store(p, v, __ATOMIC_RELAXED, __HIP_MEMORY_SCOPE_AGENT);
}
__device__ __forceinline__ u64 packft(float f, u32 tag) {
  return ((u64)tag << 32) | (u64)__float_as_uint(f);
}
__device__ __forceinline__ float dot4f(float4 a, float4 b) {
  return fmaf(a.x, b.x, fmaf(a.y, b.y, fmaf(a.z, b.z, a.w * b.w)));
}
// fast activations: v_exp_f32 + v_rcp_f32. |rel err| ~1e-6, bounded outputs.
__device__ __forceinline__ float fsig(float x) {
  return __builtin_amdgcn_rcpf(1.0f + __expf(-x));
}
__device__ __forceinline__ float ftanh(float x) {
  return 1.0f - 2.0f * __builtin_amdgcn_rcpf(1.0f + __expf(2.0f * x));
}
// Force the just-issued critical store out of the WC buffer before moving on.
// R5 lesson: without this the store lingers -> every consumer's detect slips,
// poll traffic triples, dur 9.6->28ms.
// R8 lesson: do NOT issue speculative loads after it either — any carried
// in-flight load serializes the next poll start via vmcnt ordering.
// R10 lesson: do NOT aggregate the 8 per-wave stores behind a block barrier
// either — consumers need max-over-4-waves per chunk; a full-block barrier
// before one combined store makes it max-over-8 + barrier (9.54 -> 11.05ms).
__device__ __forceinline__ void drain_vmem() {
  asm volatile("s_waitcnt vmcnt(0)" ::: "memory");
}

// Pin a loaded value into registers (opaque to the optimizer; can't be
// rematerialized as a memory load inside the loop).
__device__ __forceinline__ float4 pin4(float4 v) {
  float4 r;
  asm volatile("v_mov_b32 %0, %4\n\t"
               "v_mov_b32 %1, %5\n\t"
               "v_mov_b32 %2, %6\n\t"
               "v_mov_b32 %3, %7"
               : "=v"(r.x), "=v"(r.y), "=v"(r.z), "=v"(r.w)
               : "v"(v.x), "v"(v.y), "v"(v.z), "v"(v.w));
  return r;
}
__device__ __forceinline__ float pin1(float v) {
  float r;
  asm volatile("v_mov_b32 %0, %1" : "=v"(r) : "v"(v));
  return r;
}

// wave64 sum on the VALU pipe via DPP. Result valid in lane 63 ONLY.
template <int CTRL, int RM>
__device__ __forceinline__ float dpp_add(float x) {
  return x + __int_as_float(
      __builtin_amdgcn_update_dpp(0, __float_as_int(x), CTRL, RM, 0xf, true));
}
__device__ __forceinline__ float wsum63(float x) {
  x = dpp_add<0x111, 0xf>(x);   // row_shr:1
  x = dpp_add<0x112, 0xf>(x);   // row_shr:2
  x = dpp_add<0x114, 0xf>(x);   // row_shr:4
  x = dpp_add<0x118, 0xf>(x);   // row_shr:8  -> lanes 15/31/47/63 = row sums
  x = dpp_add<0x142, 0xa>(x);   // row_bcast:15 -> lane31, lane63 partials
  x = dpp_add<0x143, 0xc>(x);   // row_bcast:31 -> lane63 = total
  return x;
}

// ---------------- transpose fc_w [512,1024] -> fcwT [1024,512] ----------------
__global__ void k_transpose(const float* __restrict__ w, float* __restrict__ wT) {
  int idx = blockIdx.x * 256 + threadIdx.x;   // 512*1024 total
  int k = idx >> 9;
  int o = idx & 511;
  wT[idx] = w[o * 1024 + k];
}

// ---------------- persistent recurrent kernel ----------------
// 256 blocks x 512 threads (8 waves, 1 block/CU, 2 waves/SIMD).
// Blocks 0..127: layer-0, block bx owns units 8bx..8bx+7 (one per wave).
// Blocks 128..255: layer-1, same mapping.
// VERIFIED optimum (9.54-9.65 ms, reproduced twice): tagged u64 slots,
// contiguous 32B chunk per polling thread (single-producer line), serial
// incremental poll with s_sleep(1), ONE __syncthreads per step, per-wave
// lane-63 stores fired independently at each wave's own completion time,
// vmcnt(0) drain after critical stores, DPP reduce. L1 splits polling:
// threads 0-255 own h0 chunks, 256-511 own h1 chunks.
// Six structurally distinct refinements all regressed (R5-R8 consumer-side,
// R10 producer-side, R6 phase-split): this structure is the floor for the
// store->MALL->detect broadcast ring. Do not add speculative loads, extra
// barriers, or store aggregation.
__global__ __launch_bounds__(512)
__attribute__((amdgpu_waves_per_eu(2, 2)))
void k_recur(
    const float* __restrict__ x,
    const float* __restrict__ Whh0, const float* __restrict__ Wih0,
    const float* __restrict__ bih0, const float* __restrict__ bhh0,
    const float* __restrict__ Wih1, const float* __restrict__ Whh1,
    const float* __restrict__ bih1, const float* __restrict__ bhh1,
    const float* __restrict__ h0in, const float* __restrict__ c0in,
    u64* __restrict__ h0buf, u64* __restrict__ h1buf)
{
  __shared__ float h0s[2][LSTM_H];
  __shared__ float h1s[2][LSTM_H];   // layer-1 blocks only

  const int tid = threadIdx.x;       // 0..511
  const int w = tid >> 6, l = tid & 63;
  const bool lay1 = (blockIdx.x >= 128);
  const int bx = lay1 ? (int)blockIdx.x - 128 : (int)blockIdx.x;
  const int hd = 8 * bx + w;         // this wave's output unit

  if (!lay1) {
    // ===================== layer-0 blocks =====================
    float4 Whr[4][4];                // Whh0 rows for unit hd
    float  Wxr[4][8];                // Wih0; lane l holds cols l+64m
#pragma unroll
    for (int g = 0; g < 4; ++g) {
#pragma unroll
      for (int q = 0; q < 4; ++q)
        Whr[g][q] = pin4(*(const float4*)&Whh0[(size_t)(g * 1024 + hd) * 1024 + q * 256 + 4 * l]);
#pragma unroll
      for (int m = 0; m < 8; ++m)
        Wxr[g][m] = pin1(Wih0[(size_t)(g * 1024 + hd) * 512 + 64 * m + l]);
    }
    float bsum[4];
#pragma unroll
    for (int g = 0; g < 4; ++g) bsum[g] = bih0[g * 1024 + hd] + bhh0[g * 1024 + hd];
    float c = c0in[hd];

    h0s[1][tid]       = h0in[tid];
    h0s[1][tid + 512] = h0in[tid + 512];
    __syncthreads();

    // step 0: f(h0_init, x[0]) -> h0buf slot 0, tag 0
    {
      float a0 = 0.f, a1 = 0.f, a2 = 0.f, a3 = 0.f;
#pragma unroll
      for (int m = 0; m < 8; ++m) {
        float xv = x[64 * m + l];
        a0 = fmaf(Wxr[0][m], xv, a0);
        a1 = fmaf(Wxr[1][m], xv, a1);
        a2 = fmaf(Wxr[2][m], xv, a2);
        a3 = fmaf(Wxr[3][m], xv, a3);
      }
#pragma unroll
      for (int q = 0; q < 4; ++q) {
        float4 hq = *(const float4*)&h0s[1][q * 256 + 4 * l];
        a0 += dot4f(Whr[0][q], hq);
        a1 += dot4f(Whr[1][q], hq);
        a2 += dot4f(Whr[2][q], hq);
        a3 += dot4f(Whr[3][q], hq);
      }
      a0 = wsum63(a0); a1 = wsum63(a1); a2 = wsum63(a2); a3 = wsum63(a3);
      c = fsig(a1 + bsum[1]) * c + fsig(a0 + bsum[0]) * ftanh(a2 + bsum[2]);
      float hn = fsig(a3 + bsum[3]) * ftanh(c);
      if (l == 63) astore(&h0buf[hd], packft(hn, 0u));   // lane 63 holds real sums
      drain_vmem();
    }

    u64* p = &h0buf[4 * tid];        // valid for tid<256 (chunk units 4tid..+3)
#pragma unroll 1
    for (int t = 0; t < LSTM_B - 1; ++t, p += 1024) {
      const int buf = t & 1;
      const u32 tt = (u32)t;
      // x(t+1) partial gates: off the critical chain, overlaps peers' flight.
      float a0 = 0.f, a1 = 0.f, a2 = 0.f, a3 = 0.f;
#pragma unroll
      for (int m = 0; m < 8; ++m) {
        float xv = x[(size_t)(t + 1) * 512 + 64 * m + l];
        a0 = fmaf(Wxr[0][m], xv, a0);
        a1 = fmaf(Wxr[1][m], xv, a1);
        a2 = fmaf(Wxr[2][m], xv, a2);
        a3 = fmaf(Wxr[3][m], xv, a3);
      }
      // waves 0-3 poll h0(t) chunks; waves 4-7 go straight to the barrier
      if (tid < 256) {
        u64 va = 0, vb = 0, vc = 0, vd = 0;
        bool da = false, db = false, dc = false, dd = false;
        for (;;) {
          if (!da) { va = aload(p);     da = ((u32)(va >> 32) == tt); }
          if (!db) { vb = aload(p + 1); db = ((u32)(vb >> 32) == tt); }
          if (!dc) { vc = aload(p + 2); dc = ((u32)(vc >> 32) == tt); }
          if (!dd) { vd = aload(p + 3); dd = ((u32)(vd >> 32) == tt); }
          if (__all(da && db && dc && dd)) break;
          __builtin_amdgcn_s_sleep(1);
        }
        float4 hv;
        hv.x = __uint_as_float((u32)va);
        hv.y = __uint_as_float((u32)vb);
        hv.z = __uint_as_float((u32)vc);
        hv.w = __uint_as_float((u32)vd);
        *(float4*)&h0s[buf][4 * tid] = hv;
      }
      __syncthreads();
#pragma unroll
      for (int q = 0; q < 4; ++q) {
        float4 hq = *(const float4*)&h0s[buf][q * 256 + 4 * l];
        a0 += dot4f(Whr[0][q], hq);
        a1 += dot4f(Whr[1][q], hq);
        a2 += dot4f(Whr[2][q], hq);
        a3 += dot4f(Whr[3][q], hq);
      }
      a0 = wsum63(a0); a1 = wsum63(a1); a2 = wsum63(a2); a3 = wsum63(a3);
      c = fsig(a1 + bsum[1]) * c + fsig(a0 + bsum[0]) * ftanh(a2 + bsum[2]);
      float hn = fsig(a3 + bsum[3]) * ftanh(c);
      if (l == 63) astore(&h0buf[(size_t)(t + 1) * 1024 + hd], packft(hn, tt + 1));
      drain_vmem();
    }
  } else {
    // ===================== layer-1 blocks =====================
    float4 Wi[4][4], Wh[4][4];
#pragma unroll
    for (int g = 0; g < 4; ++g)
#pragma unroll
      for (int q = 0; q < 4; ++q) {
        Wi[g][q] = pin4(*(const float4*)&Wih1[(size_t)(g * 1024 + hd) * 1024 + q * 256 + 4 * l]);
        Wh[g][q] = pin4(*(const float4*)&Whh1[(size_t)(g * 1024 + hd) * 1024 + q * 256 + 4 * l]);
      }
    float bsum[4];
#pragma unroll
    for (int g = 0; g < 4; ++g) bsum[g] = bih1[g * 1024 + hd] + bhh1[g * 1024 + hd];
    float c = c0in[1024 + hd];
    if (l == 63) astore(&h1buf[hd], packft(h0in[1024 + hd], 0u));  // seed h1(init)
    drain_vmem();

    // split polling: threads 0-255 own h0 chunk 4*tid; 256-511 own h1 chunk
    const bool ish0 = (tid < 256);
    const int ci = ish0 ? 4 * tid : 4 * (tid - 256);
    u64* p = ish0 ? &h0buf[ci] : &h1buf[ci];
#pragma unroll 1
    for (int t = 0; t < LSTM_B; ++t, p += 1024) {
      const int buf = t & 1;
      const u32 tt = (u32)t;
      // concurrent polls (h0 passes ~instantly since L0 runs ahead; h1 is the
      // rate-setter). ONE serial wait + ONE barrier per step.
      {
        u64 va = 0, vb = 0, vc = 0, vd = 0;
        bool da = false, db = false, dc = false, dd = false;
        for (;;) {
          if (!da) { va = aload(p);     da = ((u32)(va >> 32) == tt); }
          if (!db) { vb = aload(p + 1); db = ((u32)(vb >> 32) == tt); }
          if (!dc) { vc = aload(p + 2); dc = ((u32)(vc >> 32) == tt); }
          if (!dd) { vd = aload(p + 3); dd = ((u32)(vd >> 32) == tt); }
          if (__all(da && db && dc && dd)) break;
          __builtin_amdgcn_s_sleep(1);
        }
        float4 hv;
        hv.x = __uint_as_float((u32)va);
        hv.y = __uint_as_float((u32)vb);
        hv.z = __uint_as_float((u32)vc);
        hv.w = __uint_as_float((u32)vd);
        if (ish0) *(float4*)&h0s[buf][ci] = hv;
        else      *(float4*)&h1s[buf][ci] = hv;
      }
      __syncthreads();
      float a0 = 0.f, a1 = 0.f, a2 = 0.f, a3 = 0.f;
#pragma unroll
      for (int q = 0; q < 4; ++q) {
        float4 hq = *(const float4*)&h0s[buf][q * 256 + 4 * l];
        a0 += dot4f(Wi[0][q], hq);
        a1 += dot4f(Wi[1][q], hq);
        a2 += dot4f(Wi[2][q], hq);
        a3 += dot4f(Wi[3][q], hq);
      }
#pragma unroll
      for (int q = 0; q < 4; ++q) {
        float4 hq = *(const float4*)&h1s[buf][q * 256 + 4 * l];
        a0 += dot4f(Wh[0][q], hq);
        a1 += dot4f(Wh[1][q], hq);
        a2 += dot4f(Wh[2][q], hq);
        a3 += dot4f(Wh[3][q], hq);
      }
      a0 = wsum63(a0); a1 = wsum63(a1); a2 = wsum63(a2); a3 = wsum63(a3);
      c = fsig(a1 + bsum[1]) * c + fsig(a0 + bsum[0]) * ftanh(a2 + bsum[2]);
      float hn = fsig(a3 + bsum[3]) * ftanh(c);
      if (l == 63) astore(&h1buf[(size_t)(t + 1) * 1024 + hd], packft(hn, tt + 1));
      drain_vmem();
    }
  }
}

// ---------------- FC + softmax: 16 timesteps per block ----------------
__global__ __launch_bounds__(256) void k_fc(u64* __restrict__ h1buf,
                                            const float* __restrict__ fcwT,
                                            const float* __restrict__ fcb,
                                            float* __restrict__ out) {
  __shared__ float smem[16 * 1024];
  const int tid = threadIdx.x;
  const int t0 = blockIdx.x * 16;

  for (int i = 0; i < 64; ++i) {
    int e = tid + 256 * i;
    int tt = e >> 10, k = e & 1023;
    u64 v = aload(&h1buf[(size_t)(t0 + tt + 1) * 1024 + k]);
    smem[e] = __uint_as_float((u32)v);
  }
  __syncthreads();

  float acc0[16], acc1[16];
#pragma unroll
  for (int tt = 0; tt < 16; ++tt) { acc0[tt] = 0.f; acc1[tt] = 0.f; }

  for (int k0 = 0; k0 < 1024; k0 += 4) {
    float4 w0v, w1v;
    w0v.x = fcwT[(k0 + 0) * 512 + tid];       w1v.x = fcwT[(k0 + 0) * 512 + 256 + tid];
    w0v.y = fcwT[(k0 + 1) * 512 + tid];       w1v.y = fcwT[(k0 + 1) * 512 + 256 + tid];
    w0v.z = fcwT[(k0 + 2) * 512 + tid];       w1v.z = fcwT[(k0 + 2) * 512 + 256 + tid];
    w0v.w = fcwT[(k0 + 3) * 512 + tid];       w1v.w = fcwT[(k0 + 3) * 512 + 256 + tid];
    float4 hv[16];
#pragma unroll
    for (int tt = 0; tt < 16; ++tt) hv[tt] = *(const float4*)&smem[tt * 1024 + k0];
#pragma unroll
    for (int tt = 0; tt < 16; ++tt) {
      acc0[tt] += dot4f(w0v, hv[tt]);
      acc1[tt] += dot4f(w1v, hv[tt]);
    }
  }
  float bb0 = fcb[tid], bb1 = fcb[tid + 256];
  __syncthreads();  // done reading h1 tile; alias smem as logits [16][512]
#pragma unroll
  for (int tt = 0; tt < 16; ++tt) {
    smem[tt * 512 + tid] = acc0[tt] + bb0;
    smem[tt * 512 + 256 + tid] = acc1[tt] + bb1;
  }
  __syncthreads();

  const int wv = tid >> 6, l = tid & 63;
  for (int r = 0; r < 4; ++r) {
    int tt = wv * 4 + r;
    float v[8];
    float mx = -3.4e38f;
#pragma unroll
    for (int m = 0; m < 8; ++m) { v[m] = smem[tt * 512 + m * 64 + l]; mx = fmaxf(mx, v[m]); }
#pragma unroll
    for (int s = 1; s < 64; s <<= 1) mx = fmaxf(mx, __shfl_xor(mx, s, 64));
    float sum = 0.f;
#pragma unroll
    for (int m = 0; m < 8; ++m) { v[m] = expf(v[m] - mx); sum += v[m]; }
#pragma unroll
    for (int s = 1; s < 64; s <<= 1) sum += __shfl_xor(sum, s, 64);
    float inv = 1.0f / sum;
#pragma unroll
    for (int m = 0; m < 8; ++m) out[(size_t)(t0 + tt) * 512 + m * 64 + l] = v[m] * inv;
  }
}

extern "C" void kernel_launch(void* const* d_in, const int* in_sizes, int n_in,
                              void* d_out, int out_size, void* d_ws, size_t ws_size,
                              hipStream_t stream) {
  const float* x    = (const float*)d_in[0];
  const float* Wih0 = (const float*)d_in[1];
  const float* Whh0 = (const float*)d_in[2];
  const float* bih0 = (const float*)d_in[3];
  const float* bhh0 = (const float*)d_in[4];
  const float* Wih1 = (const float*)d_in[5];
  const float* Whh1 = (const float*)d_in[6];
  const float* bih1 = (const float*)d_in[7];
  const float* bhh1 = (const float*)d_in[8];
  const float* h0in = (const float*)d_in[9];
  const float* c0in = (const float*)d_in[10];
  const float* fcw  = (const float*)d_in[11];
  const float* fcb  = (const float*)d_in[12];
  float* out = (float*)d_out;

  // workspace: h0buf (B slots) | h1buf (B+1 slots) | fcwT  -> ~69 MB
  u64* h0buf = (u64*)d_ws;
  u64* h1buf = h0buf + (size_t)LSTM_B * 1024;
  float* fcwT = (float*)(h1buf + (size_t)(LSTM_B + 1) * 1024);

  hipLaunchKernelGGL(k_transpose, dim3((512 * 1024) / 256), dim3(256), 0, stream, fcw, fcwT);
  hipLaunchKernelGGL(k_recur, dim3(256), dim3(512), 0, stream,
                     x, Whh0, Wih0, bih0, bhh0, Wih1, Whh1, bih1, bhh1,
                     h0in, c0in, h0buf, h1buf);
  hipLaunchKernelGGL(k_fc, dim3(LSTM_B / 16), dim3(256), 0, stream, h1buf, fcwT, fcb, out);
}